// Round 3
// baseline (257.806 us; speedup 1.0000x reference)
//
#include <hip/hip_runtime.h>

// SNN conv layer: 3x3x16->64 conv (SAME, stride 1) on 512x512 NHWC,
// + old_potentials, threshold 1.0 -> (spikes, reset potentials).
// fp32 direct conv. R2: weights read from global (L1/L2-resident, 36KB),
// LDS only for the input tile (23KB) -> 4 blocks/CU fully co-resident grid.
// R3: native vector type for nontemporal builtins (float4 is a class -> rejected).

#define H 512
#define W 512
#define CI 16
#define CO 64
#define TX 32           // block x-pixel tile
#define TY 8            // block y-pixel tile
#define LDS_XS 36       // padded x stride for input tile (34 used)

typedef float v4f __attribute__((ext_vector_type(4)));

__global__ __launch_bounds__(256, 4)
void snn_conv_kernel(const float* __restrict__ in,
                     const float* __restrict__ w,
                     const float* __restrict__ oldp,
                     float* __restrict__ out_spk,
                     float* __restrict__ out_pot)
{
    // input tile: rows [ty0-1, ty0+TY], x [tx0-1, tx0+TX], layout [y][ci][x]
    __shared__ float s_in[(TY + 2) * CI * LDS_XS];   // 10*16*36 = 5760 floats = 23 KB

    const int tid = threadIdx.x;
    const int bx = blockIdx.x & 15;        // 512/32 = 16 tiles in x
    const int by = blockIdx.x >> 4;        // 64 tiles in y
    const int tx0 = bx * TX;
    const int ty0 = by * TY;

    // ---- stage input tile with NHWC -> [y][ci][x] transpose, zero halo
    for (int idx = tid; idx < (TY + 2) * (TX + 2); idx += 256) {
        const int ly = idx / (TX + 2);
        const int lx = idx - ly * (TX + 2);
        const int gy = ty0 + ly - 1;
        const int gx = tx0 + lx - 1;
        v4f v[4];
        if (gy >= 0 && gy < H && gx >= 0 && gx < W) {
            const v4f* p = (const v4f*)(in + (gy * W + gx) * CI);
            v[0] = p[0]; v[1] = p[1]; v[2] = p[2]; v[3] = p[3];
        } else {
            v[0] = v[1] = v[2] = v[3] = (v4f)(0.f);
        }
        const float* t = (const float*)v;
        float* dst = s_in + ly * (CI * LDS_XS) + lx;
        #pragma unroll
        for (int c = 0; c < CI; ++c)
            dst[c * LDS_XS] = t[c];     // stride 36 -> 2-way bank alias (free)
    }
    __syncthreads();

    // ---- thread mapping: 8 consecutive x-pixels x 8 channels
    const int cog = (tid & 7) * 8;         // output-channel base
    const int pg  = tid >> 3;              // 0..31 pixel group
    const int px  = (pg & 3) * 8;          // x sub-tile base within block tile
    const int py  = pg >> 2;               // 0..7 row within block tile

    float acc[8][8];
    #pragma unroll
    for (int xi = 0; xi < 8; ++xi)
        #pragma unroll
        for (int c = 0; c < 8; ++c)
            acc[xi][c] = 0.f;

    for (int ky = 0; ky < 3; ++ky) {
        const float* irow = s_in + (py + ky) * (CI * LDS_XS) + px;
        const float* wky = w + ky * 3 * CI * CO + cog;   // + kx*CI*CO + ci*CO
        #pragma unroll 2
        for (int ci = 0; ci < CI; ++ci) {
            const float* ir = irow + ci * LDS_XS;
            float iv[10];
            *(v4f*)&iv[0] = *(const v4f*)(ir);
            *(v4f*)&iv[4] = *(const v4f*)(ir + 4);
            iv[8] = ir[8];
            iv[9] = ir[9];
            // weights: 8 lanes/wave share each address -> L1 broadcast, 36KB resident
            const float* wr = wky + ci * CO;
            float wv[3][8];
            #pragma unroll
            for (int kx = 0; kx < 3; ++kx) {
                *(v4f*)&wv[kx][0] = *(const v4f*)(wr + kx * CI * CO);
                *(v4f*)&wv[kx][4] = *(const v4f*)(wr + kx * CI * CO + 4);
            }
            #pragma unroll
            for (int kx = 0; kx < 3; ++kx)
                #pragma unroll
                for (int xi = 0; xi < 8; ++xi)
                    #pragma unroll
                    for (int c = 0; c < 8; ++c)
                        acc[xi][c] = fmaf(iv[xi + kx], wv[kx][c], acc[xi][c]);
        }
    }

    // ---- epilogue: add old potential, threshold, spike + reset
    // oldp / outputs are stream-once (201 MB) -> nontemporal to keep
    // weights + input rows resident in L1/L2.
    const int gy = ty0 + py;
    #pragma unroll
    for (int xi = 0; xi < 8; ++xi) {
        const int gx = tx0 + px + xi;
        const int base = (gy * W + gx) * CO + cog;
        v4f old0 = __builtin_nontemporal_load((const v4f*)(oldp + base));
        v4f old1 = __builtin_nontemporal_load((const v4f*)(oldp + base) + 1);
        float old[8];
        *(v4f*)&old[0] = old0;
        *(v4f*)&old[4] = old1;
        float spk[8], pot[8];
        #pragma unroll
        for (int c = 0; c < 8; ++c) {
            const float np = acc[xi][c] + old[c];
            const bool s = (np >= 1.0f);
            spk[c] = s ? 1.0f : 0.0f;
            pot[c] = s ? 0.0f : np;
        }
        __builtin_nontemporal_store(*(const v4f*)&spk[0], (v4f*)(out_spk + base));
        __builtin_nontemporal_store(*(const v4f*)&spk[4], (v4f*)(out_spk + base) + 1);
        __builtin_nontemporal_store(*(const v4f*)&pot[0], (v4f*)(out_pot + base));
        __builtin_nontemporal_store(*(const v4f*)&pot[4], (v4f*)(out_pot + base) + 1);
    }
}

extern "C" void kernel_launch(void* const* d_in, const int* in_sizes, int n_in,
                              void* d_out, int out_size, void* d_ws, size_t ws_size,
                              hipStream_t stream) {
    const float* in   = (const float*)d_in[0];   // (1,512,512,16)
    const float* w    = (const float*)d_in[1];   // (3,3,16,64)
    const float* oldp = (const float*)d_in[2];   // (1,512,512,64)
    float* out_spk = (float*)d_out;              // (1,512,512,64) spikes
    float* out_pot = out_spk + (size_t)H * W * CO; // (1,512,512,64) new potentials

    const int grid = (W / TX) * (H / TY);        // 16 * 64 = 1024 blocks -> 4/CU, no tail
    snn_conv_kernel<<<grid, 256, 0, stream>>>(in, w, oldp, out_spk, out_pot);
}

// Round 4
// 221.539 us; speedup vs baseline: 1.1637x; 1.1637x over previous
//
#include <hip/hip_runtime.h>

// SNN conv layer: 3x3x16->64 conv (SAME, stride 1) on 512x512 NHWC,
// + old_potentials, threshold 1.0 -> (spikes, reset potentials).
// fp32 direct conv, LDS weights + LDS input tile.
// R4: 512-thread blocks, TY=16 -> LDS 78.3KB, 2 blocks/CU = 4 waves/SIMD
//     (R1 was 2 waves/SIMD @ 40% VALUBusy; R3 showed global weight reads
//      regress despite higher occupancy, and nt stores inflate WRITE_SIZE).

#define H 512
#define W 512
#define CI 16
#define CO 64
#define TX 32           // block x-pixel tile
#define TY 16           // block y-pixel tile
#define LDS_XS 36       // padded x stride for input tile (34 used)

typedef float v4f __attribute__((ext_vector_type(4)));

__global__ __launch_bounds__(512, 4)
void snn_conv_kernel(const float* __restrict__ in,
                     const float* __restrict__ w,
                     const float* __restrict__ oldp,
                     float* __restrict__ out_spk,
                     float* __restrict__ out_pot)
{
    // input tile: rows [ty0-1, ty0+TY], x [tx0-1, tx0+TX], layout [y][ci][x]
    __shared__ float s_in[(TY + 2) * CI * LDS_XS];   // 18*16*36 = 10368 floats = 41.5 KB
    __shared__ float s_w[9 * CI * CO];               // 9216 floats = 36.9 KB

    const int tid = threadIdx.x;
    const int bx = blockIdx.x & 15;        // 512/32 = 16 tiles in x
    const int by = blockIdx.x >> 4;        // 32 tiles in y
    const int tx0 = bx * TX;
    const int ty0 = by * TY;

    // ---- stage weights: 9216 floats = 2304 float4, coalesced
    {
        const v4f* wsrc = (const v4f*)w;
        v4f* wdst = (v4f*)s_w;
        for (int idx = tid; idx < 9 * CI * CO / 4; idx += 512)
            wdst[idx] = wsrc[idx];
    }

    // ---- stage input tile with NHWC -> [y][ci][x] transpose, zero halo
    for (int idx = tid; idx < (TY + 2) * (TX + 2); idx += 512) {
        const int ly = idx / (TX + 2);
        const int lx = idx - ly * (TX + 2);
        const int gy = ty0 + ly - 1;
        const int gx = tx0 + lx - 1;
        v4f v[4];
        if (gy >= 0 && gy < H && gx >= 0 && gx < W) {
            const v4f* p = (const v4f*)(in + (gy * W + gx) * CI);
            v[0] = p[0]; v[1] = p[1]; v[2] = p[2]; v[3] = p[3];
        } else {
            v[0] = v[1] = v[2] = v[3] = (v4f)(0.f);
        }
        const float* t = (const float*)v;
        float* dst = s_in + ly * (CI * LDS_XS) + lx;
        #pragma unroll
        for (int c = 0; c < CI; ++c)
            dst[c * LDS_XS] = t[c];     // stride 36 -> 2-way bank alias (free)
    }
    __syncthreads();

    // ---- thread mapping: 8 consecutive x-pixels x 8 channels
    const int cog = (tid & 7) * 8;         // output-channel base
    const int pg  = tid >> 3;              // 0..63 pixel group
    const int px  = (pg & 3) * 8;          // x sub-tile base within block tile
    const int py  = pg >> 2;               // 0..15 row within block tile

    float acc[8][8];
    #pragma unroll
    for (int xi = 0; xi < 8; ++xi)
        #pragma unroll
        for (int c = 0; c < 8; ++c)
            acc[xi][c] = 0.f;

    for (int ky = 0; ky < 3; ++ky) {
        const float* irow = s_in + (py + ky) * (CI * LDS_XS) + px;
        const float* wrow = s_w + ky * 3 * CI * CO + cog;
        #pragma unroll 1
        for (int ci = 0; ci < CI; ++ci) {
            const float* ir = irow + ci * LDS_XS;
            float iv[10];
            *(v4f*)&iv[0] = *(const v4f*)(ir);        // 16B-aligned (36-fl stride = 144B)
            *(v4f*)&iv[4] = *(const v4f*)(ir + 4);
            iv[8] = ir[8];
            iv[9] = ir[9];
            const float* wr = wrow + ci * CO;
            #pragma unroll
            for (int kx = 0; kx < 3; ++kx) {
                float wv[8];
                *(v4f*)&wv[0] = *(const v4f*)(wr + kx * CI * CO);
                *(v4f*)&wv[4] = *(const v4f*)(wr + kx * CI * CO + 4);
                #pragma unroll
                for (int xi = 0; xi < 8; ++xi)
                    #pragma unroll
                    for (int c = 0; c < 8; ++c)
                        acc[xi][c] = fmaf(iv[xi + kx], wv[c], acc[xi][c]);
            }
        }
    }

    // ---- epilogue: add old potential, threshold, spike + reset (plain stores:
    // R3 showed nontemporal stores inflate WRITE_SIZE 131->153 MB)
    const int gy = ty0 + py;
    #pragma unroll
    for (int xi = 0; xi < 8; ++xi) {
        const int gx = tx0 + px + xi;
        const int base = (gy * W + gx) * CO + cog;
        float old[8];
        *(v4f*)&old[0] = *(const v4f*)(oldp + base);
        *(v4f*)&old[4] = *(const v4f*)(oldp + base + 4);
        float spk[8], pot[8];
        #pragma unroll
        for (int c = 0; c < 8; ++c) {
            const float np = acc[xi][c] + old[c];
            const bool s = (np >= 1.0f);
            spk[c] = s ? 1.0f : 0.0f;
            pot[c] = s ? 0.0f : np;
        }
        *(v4f*)(out_spk + base)     = *(const v4f*)&spk[0];
        *(v4f*)(out_spk + base + 4) = *(const v4f*)&spk[4];
        *(v4f*)(out_pot + base)     = *(const v4f*)&pot[0];
        *(v4f*)(out_pot + base + 4) = *(const v4f*)&pot[4];
    }
}

extern "C" void kernel_launch(void* const* d_in, const int* in_sizes, int n_in,
                              void* d_out, int out_size, void* d_ws, size_t ws_size,
                              hipStream_t stream) {
    const float* in   = (const float*)d_in[0];   // (1,512,512,16)
    const float* w    = (const float*)d_in[1];   // (3,3,16,64)
    const float* oldp = (const float*)d_in[2];   // (1,512,512,64)
    float* out_spk = (float*)d_out;              // (1,512,512,64) spikes
    float* out_pot = out_spk + (size_t)H * W * CO; // (1,512,512,64) new potentials

    const int grid = (W / TX) * (H / TY);        // 16 * 32 = 512 blocks -> exactly 2/CU
    snn_conv_kernel<<<grid, 512, 0, stream>>>(in, w, oldp, out_spk, out_pot);
}

// Round 5
// 219.100 us; speedup vs baseline: 1.1767x; 1.0111x over previous
//
#include <hip/hip_runtime.h>

// SNN conv layer: 3x3x16->64 conv (SAME) on 512x512 NHWC + old_potentials,
// threshold 1.0 -> (spikes, reset potentials).
// R5: bf16 implicit-GEMM via mfma_f32_16x16x32_bf16.
//   GEMM view: M=HW pixels, N=64 co, K=144 (9 taps x 16 ci), 2 taps per K=32
//   MFMA step, 5th step = tap 8 + reg-zeroed pad.
//   fp32 path was VALU-issue-bound at ~31us of pure FMA (R4: VALUBusy 43%,
//   dur 83.5us); MFMA makes compute ~3us -> memory-bound target ~40us.

#define H 512
#define W 512
#define CI 16
#define CO 64
#define TX 32
#define TY 8
#define XT 34          // staged x extent (TX + halo)
#define YT 10          // staged y extent (TY + halo)
#define PIX_US 24      // ushorts per pixel slot (16 used; 48B stride -> 2-way banks)
#define KS 152         // s_w k-stride in elements (304B -> 12-bank stride)

typedef float v4f __attribute__((ext_vector_type(4)));
typedef float f32x4 __attribute__((ext_vector_type(4)));
typedef short short8 __attribute__((ext_vector_type(8)));
typedef unsigned int uint4v __attribute__((ext_vector_type(4)));

__device__ __forceinline__ unsigned int pack2bf(float f0, float f1) {
    // round-to-nearest-even bf16 truncation of two floats, packed
    unsigned u0 = __builtin_bit_cast(unsigned, f0);
    unsigned u1 = __builtin_bit_cast(unsigned, f1);
    u0 = (u0 + 0x7FFFu + ((u0 >> 16) & 1u)) >> 16;
    u1 = (u1 + 0x7FFFu + ((u1 >> 16) & 1u)) >> 16;
    return u0 | (u1 << 16);
}

__global__ __launch_bounds__(256, 3)
void snn_conv_mfma(const float* __restrict__ in,
                   const float* __restrict__ w,
                   const float* __restrict__ oldp,
                   float* __restrict__ out_spk,
                   float* __restrict__ out_pot)
{
    __shared__ unsigned short s_in[YT * XT * PIX_US];   // 16320 B, [y][x][16 bf16]
    __shared__ unsigned short s_w[CO * KS];             // 19456 B, [n][k] bf16

    const int tid = threadIdx.x;
    const int bx = blockIdx.x & 15;        // 16 tiles in x
    const int by = blockIdx.x >> 4;        // 64 tiles in y
    const int tx0 = bx * TX, ty0 = by * TY;

    // ---- stage weights -> s_w[n][k] bf16 (transposed from w[k][n])
    {
        const int n  = tid & 63;
        const int kq = tid >> 6;                 // 0..3, 36 k-values each
        #pragma unroll
        for (int kk = 0; kk < 18; ++kk) {
            const int k = kq * 36 + kk * 2;
            const float f0 = w[k * CO + n];      // lanes n contiguous -> coalesced
            const float f1 = w[(k + 1) * CO + n];
            *(unsigned int*)&s_w[n * KS + k] = pack2bf(f0, f1);
        }
    }

    // ---- stage input tile bf16, zero halo
    for (int idx = tid; idx < YT * XT; idx += 256) {
        const int ly = idx / XT, lx = idx - ly * XT;
        const int gy = ty0 + ly - 1, gx = tx0 + lx - 1;
        uint4v pk0, pk1;
        if ((unsigned)gy < H && (unsigned)gx < W) {
            const v4f* p = (const v4f*)(in + (gy * W + gx) * CI);
            v4f a = p[0], b = p[1], c = p[2], d = p[3];
            pk0 = (uint4v){pack2bf(a.x, a.y), pack2bf(a.z, a.w),
                           pack2bf(b.x, b.y), pack2bf(b.z, b.w)};
            pk1 = (uint4v){pack2bf(c.x, c.y), pack2bf(c.z, c.w),
                           pack2bf(d.x, d.y), pack2bf(d.z, d.w)};
        } else {
            pk0 = (uint4v)0u;
            pk1 = (uint4v)0u;
        }
        uint4v* dst = (uint4v*)&s_in[idx * PIX_US];   // 48B slot, 16B-aligned
        dst[0] = pk0;
        dst[1] = pk1;
    }
    __syncthreads();

    // ---- wave-level implicit GEMM: wave handles 2 rows x 32 px = 4 M-tiles, all 64 co
    const int lane = tid & 63;
    const int wv   = tid >> 6;       // wave 0..3 -> rows 2wv, 2wv+1
    const int r    = lane & 15;      // m within M-tile (A) / n within N-tile (B,C)
    const int quad = lane >> 4;      // 0..3
    const int half = quad & 1;       // ci-half for A
    const int tsel = quad >> 1;      // tap parity within K-step

    f32x4 acc[4][4] = {};            // [mt][nt]

    int abase[4];
    #pragma unroll
    for (int mt = 0; mt < 4; ++mt) {
        const int rl = 2 * wv + (mt >> 1);          // local pixel row
        const int xl = (mt & 1) * 16 + r;           // local pixel x
        abase[mt] = (rl * XT + xl) * PIX_US + half * 8;
    }

    const short8 zero8 = {0, 0, 0, 0, 0, 0, 0, 0};

    #pragma unroll
    for (int ks5 = 0; ks5 < 5; ++ks5) {
        const int t0 = ks5 * 2;
        const int t1 = (ks5 == 4) ? 8 : ks5 * 2 + 1;
        const int off0 = ((t0 / 3) * XT + (t0 % 3)) * PIX_US;  // compile-time
        const int off1 = ((t1 / 3) * XT + (t1 % 3)) * PIX_US;  // compile-time
        const int aoff = tsel ? off1 : off0;
        // B: lane reads k = koff..koff+7 at row n = nt*16 + r
        const int koff = (ks5 < 4) ? (ks5 * 32 + quad * 8) : (128 + half * 8);

        short8 bf[4];
        #pragma unroll
        for (int nt = 0; nt < 4; ++nt)
            bf[nt] = *(const short8*)&s_w[(nt * 16 + r) * KS + koff];

        short8 af[4];
        #pragma unroll
        for (int mt = 0; mt < 4; ++mt) {
            short8 a = *(const short8*)&s_in[abase[mt] + aoff];
            if (ks5 == 4) a = (quad >= 2) ? zero8 : a;   // zero pad k=144..159
            af[mt] = a;
        }

        #pragma unroll
        for (int mt = 0; mt < 4; ++mt)
            #pragma unroll
            for (int nt = 0; nt < 4; ++nt)
                acc[mt][nt] = __builtin_amdgcn_mfma_f32_16x16x32_bf16(
                    af[mt], bf[nt], acc[mt][nt], 0, 0, 0);
    }

    // ---- epilogue: C/D layout col=lane&15 (co), row=quad*4+reg (pixel)
    #pragma unroll
    for (int mt = 0; mt < 4; ++mt) {
        const int gy  = ty0 + 2 * wv + (mt >> 1);
        const int gxb = tx0 + (mt & 1) * 16 + quad * 4;
        #pragma unroll
        for (int reg = 0; reg < 4; ++reg) {
            const int pix = gy * W + gxb + reg;
            const int base = pix * CO + r;
            #pragma unroll
            for (int nt = 0; nt < 4; ++nt) {
                const int idx = base + nt * 16;
                const float np = acc[mt][nt][reg] + oldp[idx];
                const bool s = (np >= 1.0f);
                out_spk[idx] = s ? 1.0f : 0.0f;
                out_pot[idx] = s ? 0.0f : np;
            }
        }
    }
}

extern "C" void kernel_launch(void* const* d_in, const int* in_sizes, int n_in,
                              void* d_out, int out_size, void* d_ws, size_t ws_size,
                              hipStream_t stream) {
    const float* in   = (const float*)d_in[0];     // (1,512,512,16)
    const float* w    = (const float*)d_in[1];     // (3,3,16,64)
    const float* oldp = (const float*)d_in[2];     // (1,512,512,64)
    float* out_spk = (float*)d_out;
    float* out_pot = out_spk + (size_t)H * W * CO;

    const int grid = (W / TX) * (H / TY);          // 1024 blocks x 256 thr
    snn_conv_mfma<<<grid, 256, 0, stream>>>(in, w, oldp, out_spk, out_pot);
}